// Round 8
// baseline (347.754 us; speedup 1.0000x reference)
//
#include <hip/hip_runtime.h>

// SimplePoseGNN on MI355X — round 8.
// fp32 in/out; internal bf16 + fp32 accumulation; bf16 MFMA GEMMs.
// conv1: NO GEMM1 (rank-3 algebra: h1_pre = t·EW1s + C0, fp32-exact), NO LDS —
// y built per-lane directly in MFMA A-layout; GEMM2 (y*n_out)@W2 -> h1w; pose
// residual R3 via a 5th B-tile (Wout^T padded to 16) in wave 0. k_gconv: register
// gather of H1W rows + bn/relu + pose dot (unchanged from r7). Graph mean via
// binary search. rowstats fused into k_fill (edge-parallel atomics into Traw).

#define NN 139264
#define EE 278528
#define GG 8192
#define NBLK 544    // NN/256
#define EBLK 1088   // EE/256

typedef float f32x4 __attribute__((ext_vector_type(4)));
typedef __bf16 bf16x8 __attribute__((ext_vector_type(8)));
typedef unsigned short u16x8 __attribute__((ext_vector_type(8)));

__device__ __forceinline__ float bf2f(unsigned short u) {
    unsigned int i = ((unsigned int)u) << 16;
    float f;
    __builtin_memcpy(&f, &i, 4);
    return f;
}
__device__ __forceinline__ unsigned short f2bf(float f) {
    unsigned int i;
    __builtin_memcpy(&i, &f, 4);
    i += 0x7fffu + ((i >> 16) & 1u);   // round-to-nearest-even
    return (unsigned short)(i >> 16);
}
__device__ __forceinline__ unsigned short bfbits(float f) {
    __bf16 b = (__bf16)f;              // native cvt (RNE), pairs into v_cvt_pk_bf16_f32
    return __builtin_bit_cast(unsigned short, b);
}

// ---------------- workspace layout (bytes) ----------------
#define OFF_DEG_OUT ((size_t)0)
#define OFF_DEG_IN  ((size_t)557056)
#define OFF_TRAW    ((size_t)1114112)
#define ZERO_BYTES  ((size_t)2785280)
#define OFF_NOUT    ((size_t)2785280)
#define OFF_NIN     ((size_t)3342336)
#define OFF_ROWPTR  ((size_t)3899392)
#define OFF_CURSOR  ((size_t)4460544)
#define OFF_CSRS    ((size_t)5017600)
#define OFF_WT2     ((size_t)6131712)
#define OFF_WTA     ((size_t)6262784)
#define OFF_WTB     ((size_t)6393856)
#define OFF_WTCLS   ((size_t)6524928)
#define OFF_WOT     ((size_t)6557696)
#define OFF_BNS     ((size_t)6565888)
#define OFF_BNH     ((size_t)6572032)
#define OFF_EW1S    ((size_t)6578176)
#define OFF_C0      ((size_t)6581248)
#define OFF_BSUM    ((size_t)6582272)
#define OFF_R3      ((size_t)6586368)
#define OFF_H1W     ((size_t)8257536)
// total ~79.6 MB

// ---------------- graph preprocessing ----------------

__global__ void k_deg(const int* __restrict__ src, const int* __restrict__ dst,
                      int* __restrict__ deg_out, int* __restrict__ deg_in) {
    int e = blockIdx.x * 256 + threadIdx.x;
    if (e < EE) {
        atomicAdd(&deg_out[src[e]], 1);
        atomicAdd(&deg_in[dst[e]], 1);
    }
}

__global__ void k_scan1(const int* __restrict__ deg, int* __restrict__ part, int* __restrict__ bsum) {
    __shared__ int sh[256];
    int t = threadIdx.x, gid = blockIdx.x * 256 + t;
    int v = deg[gid];
    sh[t] = v;
    __syncthreads();
#pragma unroll
    for (int off = 1; off < 256; off <<= 1) {
        int a = (t >= off) ? sh[t - off] : 0;
        __syncthreads();
        sh[t] += a;
        __syncthreads();
    }
    part[gid] = sh[t] - v;
    if (t == 255) bsum[blockIdx.x] = sh[t];
}

__global__ void k_scan2(int* __restrict__ bsum) {
    __shared__ int sh[1024];
    int t = threadIdx.x;
    int v = (t < NBLK) ? bsum[t] : 0;
    sh[t] = v;
    __syncthreads();
#pragma unroll
    for (int off = 1; off < 1024; off <<= 1) {
        int a = (t >= off) ? sh[t - off] : 0;
        __syncthreads();
        sh[t] += a;
        __syncthreads();
    }
    if (t < NBLK) bsum[t] = sh[t] - v;
}

// scan finalize + cursor copy + norm factors
__global__ void k_scan3(int* __restrict__ rp, const int* __restrict__ bsum, int* __restrict__ cursor,
                        const int* __restrict__ dego, const int* __restrict__ degi,
                        float* __restrict__ n_out, float* __restrict__ n_in) {
    int t = threadIdx.x, gid = blockIdx.x * 256 + t;
    int v = rp[gid] + bsum[blockIdx.x];
    rp[gid] = v;
    cursor[gid] = v;
    if (gid == 0) rp[NN] = EE;
    n_out[gid] = rsqrtf((float)max(dego[gid], 1));
    n_in[gid]  = rsqrtf((float)max(degi[gid], 1));
}

// fill CSR + edge-parallel conv1 stats: Traw[dst] += n_out[src]*{nf0, nf1, 1}
__global__ void k_fill(const int* __restrict__ src, const int* __restrict__ dst,
                       int* __restrict__ cursor, int* __restrict__ csr,
                       const float* __restrict__ n_out, const float* __restrict__ nf,
                       float* __restrict__ Traw) {
    int e = blockIdx.x * 256 + threadIdx.x;
    int d = dst[e], s = src[e];
    int pos = atomicAdd(&cursor[d], 1);
    csr[pos] = s;
    float sc = n_out[s];
    float2 p = *(const float2*)(nf + 2 * (size_t)s);
    unsafeAtomicAdd(&Traw[3 * d],     sc * p.x);
    unsafeAtomicAdd(&Traw[3 * d + 1], sc * p.y);
    unsafeAtomicAdd(&Traw[3 * d + 2], sc);
}

// ---------------- weight / bn / table prep ----------------
__global__ void k_prep(const float* __restrict__ Wc2, const float* __restrict__ Wb3a,
                       const float* __restrict__ Wb3b,
                       unsigned short* __restrict__ wt2, unsigned short* __restrict__ wta,
                       unsigned short* __restrict__ wtb,
                       const float* __restrict__ wcls, unsigned short* __restrict__ tcls,
                       const float* __restrict__ g, const float* __restrict__ b,
                       const float* __restrict__ m, const float* __restrict__ v,
                       float* __restrict__ bns, float* __restrict__ bnh,
                       const float* __restrict__ Wout, unsigned short* __restrict__ wot,
                       const float* __restrict__ Wemb, const float* __restrict__ bemb,
                       const float* __restrict__ Wc1, const float* __restrict__ bc1,
                       float* __restrict__ EW1S, float* __restrict__ C0v) {
    int t = blockIdx.x * 256 + threadIdx.x;
    int y = blockIdx.y;
    if (y < 3) {
        int k = t >> 8, n = t & 255;
        const float* w = (y == 0) ? Wc2 : (y == 1) ? Wb3a : Wb3b;
        unsigned short* o = (y == 0) ? wt2 : (y == 1) ? wta : wtb;
        o[n * 256 + k] = f2bf(w[t]);
    } else if (y == 3) {
        if (t < 16384) {
            int n = t >> 8, k = t & 255;
            tcls[t] = (n < 60) ? f2bf(wcls[k * 60 + n]) : (unsigned short)0;
        }
    } else if (y == 4) {
        if (t < 1536) {
            float inv = rsqrtf(v[t] + 1e-5f);
            float s = g[t] * inv;
            bns[t] = s;
            bnh[t] = b[t] - m[t] * s;
        }
    } else if (y == 5) {
        if (t < 4096) {
            int n = t >> 8, k = t & 255;
            wot[t] = (n < 3) ? f2bf(Wout[k * 3 + n]) : (unsigned short)0;
        }
    } else {
        if (t < 256) {
            int c = t;
            float inv = rsqrtf(v[c] + 1e-5f);
            float s0 = g[c] * inv;
            float h0 = b[c] - m[c] * s0;
            float e0 = 0.f, e1 = 0.f, e2 = 0.f;
            for (int k = 0; k < 256; k++) {
                float w = Wc1[k * 256 + c];
                e0 = fmaf(Wemb[k], w, e0);
                e1 = fmaf(Wemb[256 + k], w, e1);
                e2 = fmaf(bemb[k], w, e2);
            }
            EW1S[c]       = e0 * s0;
            EW1S[256 + c] = e1 * s0;
            EW1S[512 + c] = e2 * s0;
            C0v[c] = fmaf(bc1[c], s0, h0);
        }
    }
}

// ---------------- conv1: elementwise y-build (A-layout) + GEMM2 + Wout tile -------
// y = relu(bn1( relu(t·EW1s + C0) )) + emb_resid;  h1w = (y*n_out)@W2;
// R3 = ((y*n_out)@WoutT)/n_out.  No LDS, no barriers.
__launch_bounds__(256)
__global__ void k_conv1(const float* __restrict__ Traw, const float* __restrict__ n_in,
                        const float* __restrict__ n_out, const float* __restrict__ nf,
                        const float* __restrict__ EW1S, const float* __restrict__ C0v,
                        const float* __restrict__ bns, const float* __restrict__ bnh,
                        const float* __restrict__ Wemb, const float* __restrict__ bemb,
                        const unsigned short* __restrict__ Wt2, const unsigned short* __restrict__ wot,
                        unsigned short* __restrict__ h1w, float* __restrict__ R3) {
    int lane = threadIdx.x & 63, wave = threadIdx.x >> 6;
    int wrow = blockIdx.x * 64;
    int rsel = lane & 15, kq = lane >> 4;
    bool w0w = (wave == 0);

    // per-row scalars (4 rows per lane: rsel + 16*mt)
    float t0[4], t1[4], t2[4], f0[4], f1[4], no[4];
#pragma unroll
    for (int mt = 0; mt < 4; mt++) {
        int r = wrow + mt * 16 + rsel;
        float ni = n_in[r];
        t0[mt] = Traw[3 * r] * ni;
        t1[mt] = Traw[3 * r + 1] * ni;
        t2[mt] = Traw[3 * r + 2] * ni;
        float2 p = *(const float2*)(nf + 2 * (size_t)r);
        f0[mt] = p.x; f1[mt] = p.y;
        no[mt] = n_out[r];
    }

    f32x4 acc[4][4];
    f32x4 acc3[4];
    f32x4 zero = {0.f, 0.f, 0.f, 0.f};
#pragma unroll
    for (int i = 0; i < 4; i++) {
        acc3[i] = zero;
#pragma unroll
        for (int j = 0; j < 4; j++) acc[i][j] = zero;
    }

#pragma unroll
    for (int kt = 0; kt < 8; kt++) {
        int k0 = kt * 32 + kq * 8;
        float ew0[8], ew1[8], ew2[8], c0[8], s1[8], h1[8], we0[8], we1[8], be[8];
#pragma unroll
        for (int j = 0; j < 8; j += 4) {
            *(float4*)(ew0 + j) = *(const float4*)(EW1S + k0 + j);
            *(float4*)(ew1 + j) = *(const float4*)(EW1S + 256 + k0 + j);
            *(float4*)(ew2 + j) = *(const float4*)(EW1S + 512 + k0 + j);
            *(float4*)(c0 + j)  = *(const float4*)(C0v + k0 + j);
            *(float4*)(s1 + j)  = *(const float4*)(bns + 256 + k0 + j);
            *(float4*)(h1 + j)  = *(const float4*)(bnh + 256 + k0 + j);
            *(float4*)(we0 + j) = *(const float4*)(Wemb + k0 + j);
            *(float4*)(we1 + j) = *(const float4*)(Wemb + 256 + k0 + j);
            *(float4*)(be + j)  = *(const float4*)(bemb + k0 + j);
        }
        bf16x8 afr[4];
#pragma unroll
        for (int mt = 0; mt < 4; mt++) {
#pragma unroll
            for (int j = 0; j < 8; j++) {
                float z = fmaf(t0[mt], ew0[j], fmaf(t1[mt], ew1[j], fmaf(t2[mt], ew2[j], c0[j])));
                z = fmaxf(z, 0.f);
                z = fmaf(z, s1[j], h1[j]);
                z = fmaxf(z, 0.f);
                float y = z + fmaf(f0[mt], we0[j], fmaf(f1[mt], we1[j], be[j]));
                afr[mt][j] = (__bf16)(y * no[mt]);
            }
        }
        bf16x8 bfr[4];
#pragma unroll
        for (int nt = 0; nt < 4; nt++) {
            u16x8 bu = *(const u16x8*)(Wt2 + (size_t)(wave * 64 + nt * 16 + rsel) * 256 + k0);
            bfr[nt] = __builtin_bit_cast(bf16x8, bu);
        }
        bf16x8 bw;
        if (w0w) {
            u16x8 bu = *(const u16x8*)(wot + (size_t)rsel * 256 + k0);
            bw = __builtin_bit_cast(bf16x8, bu);
        }
#pragma unroll
        for (int mt = 0; mt < 4; mt++) {
#pragma unroll
            for (int nt = 0; nt < 4; nt++)
                acc[mt][nt] = __builtin_amdgcn_mfma_f32_16x16x32_bf16(afr[mt], bfr[nt], acc[mt][nt], 0, 0, 0);
            if (w0w)
                acc3[mt] = __builtin_amdgcn_mfma_f32_16x16x32_bf16(afr[mt], bw, acc3[mt], 0, 0, 0);
        }
    }

    // store h1w (C-frag layout)
#pragma unroll
    for (int mt = 0; mt < 4; mt++)
#pragma unroll
        for (int nt = 0; nt < 4; nt++) {
            int col = wave * 64 + nt * 16 + rsel;
#pragma unroll
            for (int r = 0; r < 4; r++) {
                int row = wrow + mt * 16 + kq * 4 + r;
                h1w[(size_t)row * 256 + col] = bfbits(acc[mt][nt][r]);
            }
        }

    // R3 from wave 0, lanes rsel<3 (col = rsel of the WoutT tile)
    if (w0w && rsel < 3) {
#pragma unroll
        for (int mt = 0; mt < 4; mt++)
#pragma unroll
            for (int r = 0; r < 4; r++) {
                int row = wrow + mt * 16 + kq * 4 + r;
                R3[(size_t)row * 3 + rsel] = acc3[mt][r] / n_out[row];
            }
    }
}

// ---------------- k_gconv: gather H1W rows + bn/relu + pose dot (no GEMM/atomics/LDS) ----
__launch_bounds__(256)
__global__ void k_gconv(const int* __restrict__ rp, const int* __restrict__ csr,
                        const float* __restrict__ n_in, const unsigned short* __restrict__ h1w,
                        const float* __restrict__ bc2,
                        const float* __restrict__ bns0, const float* __restrict__ bnh0,
                        const float* __restrict__ Wout, const float* __restrict__ bout,
                        const float* __restrict__ R3, float* __restrict__ h3d) {
    int hw = threadIdx.x >> 5;        // 0..7 half-waves
    int l = threadIdx.x & 31;
    int c0 = l * 8;                   // 8 channels per lane

    float bc[8], s0[8], h0[8], s1[8], h1v[8], w0[8], w1[8], w2[8];
#pragma unroll
    for (int j = 0; j < 8; j += 4) {
        *(float4*)(bc + j)  = *(const float4*)(bc2 + c0 + j);
        *(float4*)(s0 + j)  = *(const float4*)(bns0 + c0 + j);
        *(float4*)(h0 + j)  = *(const float4*)(bnh0 + c0 + j);
        *(float4*)(s1 + j)  = *(const float4*)(bns0 + 256 + c0 + j);
        *(float4*)(h1v + j) = *(const float4*)(bnh0 + 256 + c0 + j);
    }
#pragma unroll
    for (int j = 0; j < 8; j++) {
        const float* wp = Wout + (size_t)(c0 + j) * 3;
        w0[j] = wp[0]; w1[j] = wp[1]; w2[j] = wp[2];
    }
    float b0 = bout[0], b1 = bout[1], b2v = bout[2];

    int rbase = blockIdx.x * 64 + hw * 8;
#pragma unroll 1
    for (int i = 0; i < 8; i++) {
        int row = rbase + i;
        int e0 = rp[row], e1 = rp[row + 1];
        float a[8] = {0.f, 0.f, 0.f, 0.f, 0.f, 0.f, 0.f, 0.f};
        for (int e = e0; e < e1; e++) {
            int s = csr[e];
            u16x8 v = *(const u16x8*)(h1w + ((size_t)s << 8) + c0);
#pragma unroll
            for (int j = 0; j < 8; j++) a[j] += bf2f(v[j]);
        }
        float ni = n_in[row];
        float p0 = 0.f, p1 = 0.f, p2 = 0.f;
#pragma unroll
        for (int j = 0; j < 8; j++) {
            float y = fmaf(a[j], ni, bc[j]);
            y = fmaxf(fmaf(y, s0[j], h0[j]), 0.f);
            y = fmaxf(fmaf(y, s1[j], h1v[j]), 0.f);
            p0 = fmaf(y, w0[j], p0);
            p1 = fmaf(y, w1[j], p1);
            p2 = fmaf(y, w2[j], p2);
        }
#pragma unroll
        for (int m = 1; m < 32; m <<= 1) {
            p0 += __shfl_xor(p0, m, 32);
            p1 += __shfl_xor(p1, m, 32);
            p2 += __shfl_xor(p2, m, 32);
        }
        if (l == 0) {
            size_t o = (size_t)row * 3;
            h3d[o]     = p0 + R3[o]     + b0;
            h3d[o + 1] = p1 + R3[o + 1] + b1;
            h3d[o + 2] = p2 + R3[o + 2] + b2v;
        }
    }
}

// ---------------- fused classification head (gmean via binary search) ----------------
__launch_bounds__(256)
__global__ void k_head(const int* __restrict__ n2g, const float* __restrict__ h3d,
                       const float* __restrict__ Wci, const float* __restrict__ bci,
                       const unsigned short* __restrict__ wta, const float* __restrict__ ba,
                       const unsigned short* __restrict__ wtb, const float* __restrict__ bb,
                       const unsigned short* __restrict__ wtcls, const float* __restrict__ bcls,
                       const float* __restrict__ bns, const float* __restrict__ bnh,
                       float* __restrict__ label) {
    __shared__ unsigned char smem[65536];
    int lane = threadIdx.x & 63, wave = threadIdx.x >> 6;
    unsigned char* tileA = smem + wave * 8192;
    unsigned char* tileB = smem + 32768 + wave * 8192;
    int wrow = blockIdx.x * 64 + wave * 16;
    int rsel = lane & 15, kq = lane >> 4;
    int g = wrow + rsel;              // graph id for this lane

    int lo = 0, hi = NN;
    while (lo < hi) { int mid = (lo + hi) >> 1; if (n2g[mid] < g) lo = mid + 1; else hi = mid; }
    int s = lo;
    hi = NN;
    while (lo < hi) { int mid = (lo + hi) >> 1; if (n2g[mid] < g + 1) lo = mid + 1; else hi = mid; }
    int e = lo;
    float m0 = 0.f, m1 = 0.f, m2 = 0.f;
    for (int j = s; j < e; j++) {
        m0 += h3d[(size_t)j * 3];
        m1 += h3d[(size_t)j * 3 + 1];
        m2 += h3d[(size_t)j * 3 + 2];
    }
    float inv = 1.f / fmaxf((float)(e - s), 1.f);
    m0 *= inv; m1 *= inv; m2 *= inv;

    f32x4 zero = {0.f, 0.f, 0.f, 0.f};
    f32x4 acc[16];
#pragma unroll
    for (int i = 0; i < 16; i++) acc[i] = zero;

    // stage 1: z1 = relu(bn4(z0 @ Wa + ba)), z0 built on the fly
#pragma unroll
    for (int kt = 0; kt < 8; kt++) {
        int k0 = kt * 32 + kq * 8;
        u16x8 au;
#pragma unroll
        for (int j = 0; j < 8; j++)
            au[j] = f2bf(fmaf(m0, Wci[k0 + j], fmaf(m1, Wci[256 + k0 + j],
                         fmaf(m2, Wci[512 + k0 + j], bci[k0 + j]))));
        bf16x8 af = __builtin_bit_cast(bf16x8, au);
#pragma unroll
        for (int nt = 0; nt < 16; nt++) {
            u16x8 bu = *(const u16x8*)(wta + (size_t)(nt * 16 + rsel) * 256 + k0);
            acc[nt] = __builtin_amdgcn_mfma_f32_16x16x32_bf16(af, __builtin_bit_cast(bf16x8, bu), acc[nt], 0, 0, 0);
        }
    }
#pragma unroll
    for (int nt = 0; nt < 16; nt++) {
        int col = nt * 16 + rsel;
        float bcv = ba[col];
        float sc = bns[4 * 256 + col], h = bnh[4 * 256 + col];
#pragma unroll
        for (int r = 0; r < 4; r++) {
            float y = fmaxf(fmaf(acc[nt][r] + bcv, sc, h), 0.f);
            int rr = kq * 4 + r;
            *(unsigned short*)(tileA + rr * 512 + ((col * 2) ^ ((rr & 7) << 4))) = f2bf(y);
        }
    }

    // stage 2: z2 = relu(bn5(z1 @ Wb + bb))
#pragma unroll
    for (int i = 0; i < 16; i++) acc[i] = zero;
#pragma unroll
    for (int kt = 0; kt < 8; kt++) {
        int cb = kt * 64 + kq * 16;
        u16x8 au = *(const u16x8*)(tileA + rsel * 512 + (cb ^ ((rsel & 7) << 4)));
        bf16x8 af = __builtin_bit_cast(bf16x8, au);
        int k0 = kt * 32 + kq * 8;
#pragma unroll
        for (int nt = 0; nt < 16; nt++) {
            u16x8 bu = *(const u16x8*)(wtb + (size_t)(nt * 16 + rsel) * 256 + k0);
            acc[nt] = __builtin_amdgcn_mfma_f32_16x16x32_bf16(af, __builtin_bit_cast(bf16x8, bu), acc[nt], 0, 0, 0);
        }
    }
#pragma unroll
    for (int nt = 0; nt < 16; nt++) {
        int col = nt * 16 + rsel;
        float bcv = bb[col];
        float sc = bns[5 * 256 + col], h = bnh[5 * 256 + col];
#pragma unroll
        for (int r = 0; r < 4; r++) {
            float y = fmaxf(fmaf(acc[nt][r] + bcv, sc, h), 0.f);
            int rr = kq * 4 + r;
            *(unsigned short*)(tileB + rr * 512 + ((col * 2) ^ ((rr & 7) << 4))) = f2bf(y);
        }
    }

    // stage 3: label = z2 @ Wcls + bcls (60 cols)
    f32x4 acc3[4];
#pragma unroll
    for (int i = 0; i < 4; i++) acc3[i] = zero;
#pragma unroll
    for (int kt = 0; kt < 8; kt++) {
        int cb = kt * 64 + kq * 16;
        u16x8 au = *(const u16x8*)(tileB + rsel * 512 + (cb ^ ((rsel & 7) << 4)));
        bf16x8 af = __builtin_bit_cast(bf16x8, au);
        int k0 = kt * 32 + kq * 8;
#pragma unroll
        for (int nt = 0; nt < 4; nt++) {
            u16x8 bu = *(const u16x8*)(wtcls + (size_t)(nt * 16 + rsel) * 256 + k0);
            acc3[nt] = __builtin_amdgcn_mfma_f32_16x16x32_bf16(af, __builtin_bit_cast(bf16x8, bu), acc3[nt], 0, 0, 0);
        }
    }
    int rowb = wrow + kq * 4;
#pragma unroll
    for (int nt = 0; nt < 4; nt++) {
        int col = nt * 16 + rsel;
        if (col < 60) {
            float bcv = bcls[col];
#pragma unroll
            for (int r = 0; r < 4; r++)
                label[(size_t)(rowb + r) * 60 + col] = acc3[nt][r] + bcv;
        }
    }
}

// ---------------- launch ----------------
extern "C" void kernel_launch(void* const* d_in, const int* in_sizes, int n_in,
                              void* d_out, int out_size, void* d_ws, size_t ws_size,
                              hipStream_t stream) {
    const float* nf   = (const float*)d_in[0];
    const int* src    = (const int*)d_in[1];
    const int* dst    = (const int*)d_in[2];
    const int* n2g    = (const int*)d_in[3];
    const float* Wemb = (const float*)d_in[4];
    const float* bemb = (const float*)d_in[5];
    const float* Wc1  = (const float*)d_in[6];
    const float* bc1  = (const float*)d_in[7];
    const float* Wc2  = (const float*)d_in[8];
    const float* bc2  = (const float*)d_in[9];
    const float* bng  = (const float*)d_in[10];
    const float* bnb  = (const float*)d_in[11];
    const float* bnm  = (const float*)d_in[12];
    const float* bnv  = (const float*)d_in[13];
    const float* Wout = (const float*)d_in[14];
    const float* bout = (const float*)d_in[15];
    const float* Wci  = (const float*)d_in[16];
    const float* bci  = (const float*)d_in[17];
    const float* Wb3a = (const float*)d_in[18];
    const float* bb3a = (const float*)d_in[19];
    const float* Wb3b = (const float*)d_in[20];
    const float* bb3b = (const float*)d_in[21];
    const float* Wcls = (const float*)d_in[22];
    const float* bcls = (const float*)d_in[23];

    char* ws = (char*)d_ws;
    int* deg_out = (int*)(ws + OFF_DEG_OUT);
    int* deg_in  = (int*)(ws + OFF_DEG_IN);
    float* Traw  = (float*)(ws + OFF_TRAW);
    float* n_out = (float*)(ws + OFF_NOUT);
    float* n_inp = (float*)(ws + OFF_NIN);
    int* row_ptr = (int*)(ws + OFF_ROWPTR);
    int* cursor  = (int*)(ws + OFF_CURSOR);
    int* csr_src = (int*)(ws + OFF_CSRS);
    int* bsum    = (int*)(ws + OFF_BSUM);
    unsigned short* wt2   = (unsigned short*)(ws + OFF_WT2);
    unsigned short* wta   = (unsigned short*)(ws + OFF_WTA);
    unsigned short* wtb   = (unsigned short*)(ws + OFF_WTB);
    unsigned short* wtcls = (unsigned short*)(ws + OFF_WTCLS);
    unsigned short* wot   = (unsigned short*)(ws + OFF_WOT);
    float* bns  = (float*)(ws + OFF_BNS);
    float* bnh  = (float*)(ws + OFF_BNH);
    float* EW1S = (float*)(ws + OFF_EW1S);
    float* C0v  = (float*)(ws + OFF_C0);
    float* R3   = (float*)(ws + OFF_R3);
    unsigned short* h1w = (unsigned short*)(ws + OFF_H1W);

    float* h3d_out   = (float*)d_out;
    float* label_out = (float*)d_out + (size_t)NN * 3;

    hipMemsetAsync(ws, 0, ZERO_BYTES, stream);   // deg_out, deg_in, Traw

    k_deg<<<EBLK, 256, 0, stream>>>(src, dst, deg_out, deg_in);
    k_scan1<<<NBLK, 256, 0, stream>>>(deg_in, row_ptr, bsum);
    k_scan2<<<1, 1024, 0, stream>>>(bsum);
    k_scan3<<<NBLK, 256, 0, stream>>>(row_ptr, bsum, cursor, deg_out, deg_in, n_out, n_inp);
    k_fill<<<EBLK, 256, 0, stream>>>(src, dst, cursor, csr_src, n_out, nf, Traw);
    k_prep<<<dim3(256, 7), 256, 0, stream>>>(Wc2, Wb3a, Wb3b, wt2, wta, wtb,
                                             Wcls, wtcls, bng, bnb, bnm, bnv, bns, bnh,
                                             Wout, wot, Wemb, bemb, Wc1, bc1, EW1S, C0v);

    k_conv1<<<NN / 64, 256, 0, stream>>>(Traw, n_inp, n_out, nf, EW1S, C0v, bns, bnh,
                                         Wemb, bemb, wt2, wot, h1w, R3);
    k_gconv<<<NN / 64, 256, 0, stream>>>(row_ptr, csr_src, n_inp, h1w, bc2,
                                         bns + 512, bnh + 512, Wout, bout, R3, h3d_out);
    k_head<<<GG / 64, 256, 0, stream>>>(n2g, h3d_out, Wci, bci, wta, bb3a, wtb, bb3b,
                                        wtcls, bcls, bns, bnh, label_out);
}

// Round 9
// 246.617 us; speedup vs baseline: 1.4101x; 1.4101x over previous
//
#include <hip/hip_runtime.h>

// SimplePoseGNN on MI355X — round 9.
// fp32 in/out; internal bf16 + fp32 accumulation; bf16 MFMA GEMMs.
// conv1: cooperative y-build (each y computed ONCE: thread(wave,lane) = channels
// wave*64..+63 of row lane) from a packed 9-table TAB in LDS, swizzled tileY,
// then GEMM2 (y*n_out)@W2 + Wout residual tile; h1w stored CHANNEL-PERMUTED
// (c' = wave*64+rsel*4+nt) for 8B coalesced stores. gconv uses permuted params.
// Graph mean via binary search; fully fused classification head.

#define NN 139264
#define EE 278528
#define GG 8192
#define NBLK 544    // NN/256
#define EBLK 1088   // EE/256

typedef float f32x4 __attribute__((ext_vector_type(4)));
typedef __bf16 bf16x8 __attribute__((ext_vector_type(8)));
typedef unsigned short u16x8 __attribute__((ext_vector_type(8)));
typedef unsigned short u16x4 __attribute__((ext_vector_type(4)));

__device__ __forceinline__ float bf2f(unsigned short u) {
    unsigned int i = ((unsigned int)u) << 16;
    float f;
    __builtin_memcpy(&f, &i, 4);
    return f;
}
__device__ __forceinline__ unsigned short f2bf(float f) {
    unsigned int i;
    __builtin_memcpy(&i, &f, 4);
    i += 0x7fffu + ((i >> 16) & 1u);   // round-to-nearest-even
    return (unsigned short)(i >> 16);
}
__device__ __forceinline__ unsigned short bfbits(float f) {
    __bf16 b = (__bf16)f;
    return __builtin_bit_cast(unsigned short, b);
}

// ---------------- workspace layout (bytes) ----------------
#define OFF_DEG_OUT ((size_t)0)
#define OFF_DEG_IN  ((size_t)557056)
#define ZERO_BYTES  ((size_t)1114112)
#define OFF_T       ((size_t)1114112)
#define OFF_NOUT    ((size_t)2785280)
#define OFF_NIN     ((size_t)3342336)
#define OFF_ROWPTR  ((size_t)3899392)
#define OFF_CURSOR  ((size_t)4460544)
#define OFF_CSRS    ((size_t)5017600)
#define OFF_WT2     ((size_t)6131712)
#define OFF_WTA     ((size_t)6262784)
#define OFF_WTB     ((size_t)6393856)
#define OFF_WTCLS   ((size_t)6524928)
#define OFF_WOT     ((size_t)6557696)
#define OFF_BNS     ((size_t)6565888)
#define OFF_BNH     ((size_t)6572032)
#define OFF_TAB     ((size_t)6578176)
#define OFF_PP      ((size_t)6587392)
#define OFF_BSUM    ((size_t)6595584)
#define OFF_R3      ((size_t)6599680)
#define OFF_H1W     ((size_t)8270848)
// total ~79.6 MB

// ---------------- graph preprocessing ----------------

__global__ void k_deg(const int* __restrict__ src, const int* __restrict__ dst,
                      int* __restrict__ deg_out, int* __restrict__ deg_in) {
    int e = blockIdx.x * 256 + threadIdx.x;
    if (e < EE) {
        atomicAdd(&deg_out[src[e]], 1);
        atomicAdd(&deg_in[dst[e]], 1);
    }
}

__global__ void k_scan1(const int* __restrict__ deg, int* __restrict__ part, int* __restrict__ bsum) {
    __shared__ int sh[256];
    int t = threadIdx.x, gid = blockIdx.x * 256 + t;
    int v = deg[gid];
    sh[t] = v;
    __syncthreads();
#pragma unroll
    for (int off = 1; off < 256; off <<= 1) {
        int a = (t >= off) ? sh[t - off] : 0;
        __syncthreads();
        sh[t] += a;
        __syncthreads();
    }
    part[gid] = sh[t] - v;
    if (t == 255) bsum[blockIdx.x] = sh[t];
}

__global__ void k_scan2(int* __restrict__ bsum) {
    __shared__ int sh[1024];
    int t = threadIdx.x;
    int v = (t < NBLK) ? bsum[t] : 0;
    sh[t] = v;
    __syncthreads();
#pragma unroll
    for (int off = 1; off < 1024; off <<= 1) {
        int a = (t >= off) ? sh[t - off] : 0;
        __syncthreads();
        sh[t] += a;
        __syncthreads();
    }
    if (t < NBLK) bsum[t] = sh[t] - v;
}

__global__ void k_scan3(int* __restrict__ rp, const int* __restrict__ bsum, int* __restrict__ cursor,
                        const int* __restrict__ dego, const int* __restrict__ degi,
                        float* __restrict__ n_out, float* __restrict__ n_in) {
    int t = threadIdx.x, gid = blockIdx.x * 256 + t;
    int v = rp[gid] + bsum[blockIdx.x];
    rp[gid] = v;
    cursor[gid] = v;
    if (gid == 0) rp[NN] = EE;
    n_out[gid] = rsqrtf((float)max(dego[gid], 1));
    n_in[gid]  = rsqrtf((float)max(degi[gid], 1));
}

__global__ void k_fill(const int* __restrict__ src, const int* __restrict__ dst,
                       int* __restrict__ cursor, int* __restrict__ csr) {
    int e = blockIdx.x * 256 + threadIdx.x;
    int d = dst[e];
    int pos = atomicAdd(&cursor[d], 1);
    csr[pos] = src[e];
}

// per-row conv1 stats: T[r] = n_in[r] * { Σ sc*nf0, Σ sc*nf1, Σ sc },  sc = n_out[src]
__global__ void k_rowstats(const int* __restrict__ rp, const int* __restrict__ csr,
                           const float* __restrict__ n_out, const float* __restrict__ n_in,
                           const float* __restrict__ nf, float* __restrict__ T) {
    int r = blockIdx.x * 256 + threadIdx.x;
    int e0 = rp[r], e1 = rp[r + 1];
    float S0 = 0.f, S1 = 0.f, S2 = 0.f;
    for (int e = e0; e < e1; e++) {
        int s = csr[e];
        float sc = n_out[s];
        S0 = fmaf(sc, nf[2 * s], S0);
        S1 = fmaf(sc, nf[2 * s + 1], S1);
        S2 += sc;
    }
    float ni = n_in[r];
    T[3 * r]     = S0 * ni;
    T[3 * r + 1] = S1 * ni;
    T[3 * r + 2] = S2 * ni;
}

// ---------------- weight / bn / table prep ----------------
// TAB layout (floats): [0]ew0s [256]ew1s [512]ew2s [768]c0 [1024]s1 [1280]h1
//                      [1536]we0 [1792]we1 [2048]be     (2304 total)
// PP layout (floats):  [0]bc2p [256]s2p [512]h2p [768]s3p [1024]h3p
//                      [1280]w0p [1536]w1p [1792]w2p    (2048 total)
__global__ void k_prep(const float* __restrict__ Wc2, const float* __restrict__ Wb3a,
                       const float* __restrict__ Wb3b,
                       unsigned short* __restrict__ wt2, unsigned short* __restrict__ wta,
                       unsigned short* __restrict__ wtb,
                       const float* __restrict__ wcls, unsigned short* __restrict__ tcls,
                       const float* __restrict__ g, const float* __restrict__ b,
                       const float* __restrict__ m, const float* __restrict__ v,
                       float* __restrict__ bns, float* __restrict__ bnh,
                       const float* __restrict__ Wout, unsigned short* __restrict__ wot,
                       const float* __restrict__ Wemb, const float* __restrict__ bemb,
                       const float* __restrict__ Wc1, const float* __restrict__ bc1,
                       const float* __restrict__ bc2,
                       float* __restrict__ TAB, float* __restrict__ PP) {
    int t = blockIdx.x * 256 + threadIdx.x;
    int y = blockIdx.y;
    if (y < 3) {
        int k = t >> 8, n = t & 255;
        const float* w = (y == 0) ? Wc2 : (y == 1) ? Wb3a : Wb3b;
        unsigned short* o = (y == 0) ? wt2 : (y == 1) ? wta : wtb;
        o[n * 256 + k] = f2bf(w[t]);
    } else if (y == 3) {
        if (t < 16384) {
            int n = t >> 8, k = t & 255;
            tcls[t] = (n < 60) ? f2bf(wcls[k * 60 + n]) : (unsigned short)0;
        }
    } else if (y == 4) {
        if (t < 1536) {
            float inv = rsqrtf(v[t] + 1e-5f);
            float s = g[t] * inv;
            bns[t] = s;
            bnh[t] = b[t] - m[t] * s;
        }
    } else if (y == 5) {
        if (t < 4096) {
            int n = t >> 8, k = t & 255;
            wot[t] = (n < 3) ? f2bf(Wout[k * 3 + n]) : (unsigned short)0;
        }
    } else if (y == 6) {
        if (t < 256) {
            int c = t;
            float inv0 = rsqrtf(v[c] + 1e-5f);
            float s0 = g[c] * inv0;
            float h0 = b[c] - m[c] * s0;
            float e0 = 0.f, e1 = 0.f, e2 = 0.f;
            for (int k = 0; k < 256; k++) {
                float w = Wc1[k * 256 + c];
                e0 = fmaf(Wemb[k], w, e0);
                e1 = fmaf(Wemb[256 + k], w, e1);
                e2 = fmaf(bemb[k], w, e2);
            }
            TAB[c]        = e0 * s0;
            TAB[256 + c]  = e1 * s0;
            TAB[512 + c]  = e2 * s0;
            TAB[768 + c]  = fmaf(bc1[c], s0, h0);
            float inv1 = rsqrtf(v[256 + c] + 1e-5f);
            float s1 = g[256 + c] * inv1;
            TAB[1024 + c] = s1;
            TAB[1280 + c] = b[256 + c] - m[256 + c] * s1;
            TAB[1536 + c] = Wemb[c];
            TAB[1792 + c] = Wemb[256 + c];
            TAB[2048 + c] = bemb[c];
        }
    } else {
        if (t < 256) {
            int cp = t;                         // permuted index
            int w = cp >> 6, rs = (cp >> 2) & 15, nt = cp & 3;
            int c = w * 64 + nt * 16 + rs;      // actual channel
            PP[cp] = bc2[c];
            float inv2 = rsqrtf(v[512 + c] + 1e-5f);
            float s2 = g[512 + c] * inv2;
            PP[256 + cp] = s2;
            PP[512 + cp] = b[512 + c] - m[512 + c] * s2;
            float inv3 = rsqrtf(v[768 + c] + 1e-5f);
            float s3 = g[768 + c] * inv3;
            PP[768 + cp] = s3;
            PP[1024 + cp] = b[768 + c] - m[768 + c] * s3;
            PP[1280 + cp] = Wout[c * 3];
            PP[1536 + cp] = Wout[c * 3 + 1];
            PP[1792 + cp] = Wout[c * 3 + 2];
        }
    }
}

// ---------------- conv1: cooperative y-build + GEMM2 + Wout tile ----------------
__launch_bounds__(256)
__global__ void k_conv1(const float* __restrict__ T, const float* __restrict__ nf,
                        const float* __restrict__ TAB, const float* __restrict__ n_out,
                        const unsigned short* __restrict__ Wt2, const unsigned short* __restrict__ wot,
                        unsigned short* __restrict__ h1w, float* __restrict__ R3) {
    __shared__ float ltab[2304];
    __shared__ unsigned char tileY[64 * 512];
    int lane = threadIdx.x & 63, wave = threadIdx.x >> 6;
    int wrow = blockIdx.x * 64;
    int rsel = lane & 15, kq = lane >> 4;

    // stage TAB into LDS
    for (int i = threadIdx.x; i < 2304; i += 256) ltab[i] = TAB[i];
    __syncthreads();

    // ---- phase 1: thread (wave,lane) builds channels wave*64..+63 of row lane
    {
        int row = wrow + lane;
        float t0 = T[3 * row], t1 = T[3 * row + 1], t2 = T[3 * row + 2];
        float2 p = *(const float2*)(nf + 2 * (size_t)row);
        float f0 = p.x, f1 = p.y;
        float no = n_out[row];
        int rot = lane >> 3;
        int sw = (lane & 7) << 4;
        unsigned char* wb = tileY + lane * 512;
#pragma unroll
        for (int jj = 0; jj < 8; jj++) {
            int c = wave * 64 + (((jj + rot) & 7) << 3);
            f32x4 ew0a = *(const f32x4*)(ltab + c),        ew0b = *(const f32x4*)(ltab + c + 4);
            f32x4 ew1a = *(const f32x4*)(ltab + 256 + c),  ew1b = *(const f32x4*)(ltab + 256 + c + 4);
            f32x4 ew2a = *(const f32x4*)(ltab + 512 + c),  ew2b = *(const f32x4*)(ltab + 512 + c + 4);
            f32x4 c0a  = *(const f32x4*)(ltab + 768 + c),  c0b  = *(const f32x4*)(ltab + 768 + c + 4);
            f32x4 s1a  = *(const f32x4*)(ltab + 1024 + c), s1b  = *(const f32x4*)(ltab + 1024 + c + 4);
            f32x4 h1a  = *(const f32x4*)(ltab + 1280 + c), h1b  = *(const f32x4*)(ltab + 1280 + c + 4);
            f32x4 w0a  = *(const f32x4*)(ltab + 1536 + c), w0b  = *(const f32x4*)(ltab + 1536 + c + 4);
            f32x4 w1a  = *(const f32x4*)(ltab + 1792 + c), w1b  = *(const f32x4*)(ltab + 1792 + c + 4);
            f32x4 bea  = *(const f32x4*)(ltab + 2048 + c), beb  = *(const f32x4*)(ltab + 2048 + c + 4);
            u16x8 o;
#pragma unroll
            for (int j = 0; j < 4; j++) {
                float z = fmaf(t0, ew0a[j], fmaf(t1, ew1a[j], fmaf(t2, ew2a[j], c0a[j])));
                z = fmaxf(z, 0.f);
                z = fmaxf(fmaf(z, s1a[j], h1a[j]), 0.f);
                float yv = z + fmaf(f0, w0a[j], fmaf(f1, w1a[j], bea[j]));
                o[j] = bfbits(yv * no);
            }
#pragma unroll
            for (int j = 0; j < 4; j++) {
                float z = fmaf(t0, ew0b[j], fmaf(t1, ew1b[j], fmaf(t2, ew2b[j], c0b[j])));
                z = fmaxf(z, 0.f);
                z = fmaxf(fmaf(z, s1b[j], h1b[j]), 0.f);
                float yv = z + fmaf(f0, w0b[j], fmaf(f1, w1b[j], beb[j]));
                o[4 + j] = bfbits(yv * no);
            }
            *(u16x8*)(wb + ((c * 2) ^ sw)) = o;
        }
    }
    __syncthreads();

    // ---- phase 2: GEMM2 (tileY @ W2) + Wout residual tile (wave 0)
    bool w0w = (wave == 0);
    f32x4 acc[4][4];
    f32x4 acc3[4];
    f32x4 zero = {0.f, 0.f, 0.f, 0.f};
#pragma unroll
    for (int i = 0; i < 4; i++) {
        acc3[i] = zero;
#pragma unroll
        for (int j = 0; j < 4; j++) acc[i][j] = zero;
    }
#pragma unroll
    for (int kt = 0; kt < 8; kt++) {
        int cb = kt * 64 + kq * 16;
        int k0 = kt * 32 + kq * 8;
        bf16x8 afr[4];
#pragma unroll
        for (int mt = 0; mt < 4; mt++) {
            int ar = mt * 16 + rsel;
            u16x8 au = *(const u16x8*)(tileY + ar * 512 + (cb ^ ((ar & 7) << 4)));
            afr[mt] = __builtin_bit_cast(bf16x8, au);
        }
        bf16x8 bfr[4];
#pragma unroll
        for (int nt = 0; nt < 4; nt++) {
            u16x8 bu = *(const u16x8*)(Wt2 + (size_t)(wave * 64 + nt * 16 + rsel) * 256 + k0);
            bfr[nt] = __builtin_bit_cast(bf16x8, bu);
        }
        bf16x8 bw;
        if (w0w) {
            u16x8 bu = *(const u16x8*)(wot + (size_t)rsel * 256 + k0);
            bw = __builtin_bit_cast(bf16x8, bu);
        }
#pragma unroll
        for (int mt = 0; mt < 4; mt++) {
#pragma unroll
            for (int nt = 0; nt < 4; nt++)
                acc[mt][nt] = __builtin_amdgcn_mfma_f32_16x16x32_bf16(afr[mt], bfr[nt], acc[mt][nt], 0, 0, 0);
            if (w0w)
                acc3[mt] = __builtin_amdgcn_mfma_f32_16x16x32_bf16(afr[mt], bw, acc3[mt], 0, 0, 0);
        }
    }

    // permuted coalesced stores: channel c' = wave*64 + rsel*4 + nt
#pragma unroll
    for (int mt = 0; mt < 4; mt++) {
#pragma unroll
        for (int r = 0; r < 4; r++) {
            int row = wrow + mt * 16 + kq * 4 + r;
            u16x4 o;
#pragma unroll
            for (int nt = 0; nt < 4; nt++) o[nt] = bfbits(acc[mt][nt][r]);
            *(u16x4*)(h1w + (size_t)row * 256 + wave * 64 + rsel * 4) = o;
        }
    }

    // R3 from wave 0, lanes rsel<3
    if (w0w && rsel < 3) {
#pragma unroll
        for (int mt = 0; mt < 4; mt++)
#pragma unroll
            for (int r = 0; r < 4; r++) {
                int row = wrow + mt * 16 + kq * 4 + r;
                R3[(size_t)row * 3 + rsel] = acc3[mt][r] / n_out[row];
            }
    }
}

// ---------------- k_gconv: register gather + permuted bn/relu + pose dot ----------
__launch_bounds__(256)
__global__ void k_gconv(const int* __restrict__ rp, const int* __restrict__ csr,
                        const float* __restrict__ n_in, const unsigned short* __restrict__ h1w,
                        const float* __restrict__ PP, const float* __restrict__ bout,
                        const float* __restrict__ R3, float* __restrict__ h3d) {
    int hw = threadIdx.x >> 5;        // 0..7 half-waves
    int l = threadIdx.x & 31;
    int c0 = l * 8;                   // 8 permuted channels per lane

    float bc[8], s0[8], h0[8], s1[8], h1v[8], w0[8], w1[8], w2[8];
#pragma unroll
    for (int j = 0; j < 8; j += 4) {
        *(float4*)(bc + j)  = *(const float4*)(PP + c0 + j);
        *(float4*)(s0 + j)  = *(const float4*)(PP + 256 + c0 + j);
        *(float4*)(h0 + j)  = *(const float4*)(PP + 512 + c0 + j);
        *(float4*)(s1 + j)  = *(const float4*)(PP + 768 + c0 + j);
        *(float4*)(h1v + j) = *(const float4*)(PP + 1024 + c0 + j);
        *(float4*)(w0 + j)  = *(const float4*)(PP + 1280 + c0 + j);
        *(float4*)(w1 + j)  = *(const float4*)(PP + 1536 + c0 + j);
        *(float4*)(w2 + j)  = *(const float4*)(PP + 1792 + c0 + j);
    }
    float b0 = bout[0], b1 = bout[1], b2v = bout[2];

    int rbase = blockIdx.x * 64 + hw * 8;
#pragma unroll 1
    for (int i = 0; i < 8; i++) {
        int row = rbase + i;
        int e0 = rp[row], e1 = rp[row + 1];
        float a[8] = {0.f, 0.f, 0.f, 0.f, 0.f, 0.f, 0.f, 0.f};
        for (int e = e0; e < e1; e++) {
            int s = csr[e];
            u16x8 v = *(const u16x8*)(h1w + ((size_t)s << 8) + c0);
#pragma unroll
            for (int j = 0; j < 8; j++) a[j] += bf2f(v[j]);
        }
        float ni = n_in[row];
        float p0 = 0.f, p1 = 0.f, p2 = 0.f;
#pragma unroll
        for (int j = 0; j < 8; j++) {
            float y = fmaf(a[j], ni, bc[j]);
            y = fmaxf(fmaf(y, s0[j], h0[j]), 0.f);
            y = fmaxf(fmaf(y, s1[j], h1v[j]), 0.f);
            p0 = fmaf(y, w0[j], p0);
            p1 = fmaf(y, w1[j], p1);
            p2 = fmaf(y, w2[j], p2);
        }
#pragma unroll
        for (int m = 1; m < 32; m <<= 1) {
            p0 += __shfl_xor(p0, m, 32);
            p1 += __shfl_xor(p1, m, 32);
            p2 += __shfl_xor(p2, m, 32);
        }
        if (l == 0) {
            size_t o = (size_t)row * 3;
            h3d[o]     = p0 + R3[o]     + b0;
            h3d[o + 1] = p1 + R3[o + 1] + b1;
            h3d[o + 2] = p2 + R3[o + 2] + b2v;
        }
    }
}

// ---------------- fused classification head (gmean via binary search) ----------------
__launch_bounds__(256)
__global__ void k_head(const int* __restrict__ n2g, const float* __restrict__ h3d,
                       const float* __restrict__ Wci, const float* __restrict__ bci,
                       const unsigned short* __restrict__ wta, const float* __restrict__ ba,
                       const unsigned short* __restrict__ wtb, const float* __restrict__ bb,
                       const unsigned short* __restrict__ wtcls, const float* __restrict__ bcls,
                       const float* __restrict__ bns, const float* __restrict__ bnh,
                       float* __restrict__ label) {
    __shared__ unsigned char smem[65536];
    int lane = threadIdx.x & 63, wave = threadIdx.x >> 6;
    unsigned char* tileA = smem + wave * 8192;
    unsigned char* tileB = smem + 32768 + wave * 8192;
    int wrow = blockIdx.x * 64 + wave * 16;
    int rsel = lane & 15, kq = lane >> 4;
    int g = wrow + rsel;

    int lo = 0, hi = NN;
    while (lo < hi) { int mid = (lo + hi) >> 1; if (n2g[mid] < g) lo = mid + 1; else hi = mid; }
    int s = lo;
    hi = NN;
    while (lo < hi) { int mid = (lo + hi) >> 1; if (n2g[mid] < g + 1) lo = mid + 1; else hi = mid; }
    int e = lo;
    float m0 = 0.f, m1 = 0.f, m2 = 0.f;
    for (int j = s; j < e; j++) {
        m0 += h3d[(size_t)j * 3];
        m1 += h3d[(size_t)j * 3 + 1];
        m2 += h3d[(size_t)j * 3 + 2];
    }
    float inv = 1.f / fmaxf((float)(e - s), 1.f);
    m0 *= inv; m1 *= inv; m2 *= inv;

    f32x4 zero = {0.f, 0.f, 0.f, 0.f};
    f32x4 acc[16];
#pragma unroll
    for (int i = 0; i < 16; i++) acc[i] = zero;

    // stage 1: z1 = relu(bn4(z0 @ Wa + ba)), z0 built on the fly
#pragma unroll
    for (int kt = 0; kt < 8; kt++) {
        int k0 = kt * 32 + kq * 8;
        u16x8 au;
#pragma unroll
        for (int j = 0; j < 8; j++)
            au[j] = f2bf(fmaf(m0, Wci[k0 + j], fmaf(m1, Wci[256 + k0 + j],
                         fmaf(m2, Wci[512 + k0 + j], bci[k0 + j]))));
        bf16x8 af = __builtin_bit_cast(bf16x8, au);
#pragma unroll
        for (int nt = 0; nt < 16; nt++) {
            u16x8 bu = *(const u16x8*)(wta + (size_t)(nt * 16 + rsel) * 256 + k0);
            acc[nt] = __builtin_amdgcn_mfma_f32_16x16x32_bf16(af, __builtin_bit_cast(bf16x8, bu), acc[nt], 0, 0, 0);
        }
    }
#pragma unroll
    for (int nt = 0; nt < 16; nt++) {
        int col = nt * 16 + rsel;
        float bcv = ba[col];
        float sc = bns[4 * 256 + col], h = bnh[4 * 256 + col];
#pragma unroll
        for (int r = 0; r < 4; r++) {
            float y = fmaxf(fmaf(acc[nt][r] + bcv, sc, h), 0.f);
            int rr = kq * 4 + r;
            *(unsigned short*)(tileA + rr * 512 + ((col * 2) ^ ((rr & 7) << 4))) = f2bf(y);
        }
    }

    // stage 2: z2 = relu(bn5(z1 @ Wb + bb))
#pragma unroll
    for (int i = 0; i < 16; i++) acc[i] = zero;
#pragma unroll
    for (int kt = 0; kt < 8; kt++) {
        int cb = kt * 64 + kq * 16;
        u16x8 au = *(const u16x8*)(tileA + rsel * 512 + (cb ^ ((rsel & 7) << 4)));
        bf16x8 af = __builtin_bit_cast(bf16x8, au);
        int k0 = kt * 32 + kq * 8;
#pragma unroll
        for (int nt = 0; nt < 16; nt++) {
            u16x8 bu = *(const u16x8*)(wtb + (size_t)(nt * 16 + rsel) * 256 + k0);
            acc[nt] = __builtin_amdgcn_mfma_f32_16x16x32_bf16(af, __builtin_bit_cast(bf16x8, bu), acc[nt], 0, 0, 0);
        }
    }
#pragma unroll
    for (int nt = 0; nt < 16; nt++) {
        int col = nt * 16 + rsel;
        float bcv = bb[col];
        float sc = bns[5 * 256 + col], h = bnh[5 * 256 + col];
#pragma unroll
        for (int r = 0; r < 4; r++) {
            float y = fmaxf(fmaf(acc[nt][r] + bcv, sc, h), 0.f);
            int rr = kq * 4 + r;
            *(unsigned short*)(tileB + rr * 512 + ((col * 2) ^ ((rr & 7) << 4))) = f2bf(y);
        }
    }

    // stage 3: label = z2 @ Wcls + bcls (60 cols)
    f32x4 acc3[4];
#pragma unroll
    for (int i = 0; i < 4; i++) acc3[i] = zero;
#pragma unroll
    for (int kt = 0; kt < 8; kt++) {
        int cb = kt * 64 + kq * 16;
        u16x8 au = *(const u16x8*)(tileB + rsel * 512 + (cb ^ ((rsel & 7) << 4)));
        bf16x8 af = __builtin_bit_cast(bf16x8, au);
        int k0 = kt * 32 + kq * 8;
#pragma unroll
        for (int nt = 0; nt < 4; nt++) {
            u16x8 bu = *(const u16x8*)(wtcls + (size_t)(nt * 16 + rsel) * 256 + k0);
            acc3[nt] = __builtin_amdgcn_mfma_f32_16x16x32_bf16(af, __builtin_bit_cast(bf16x8, bu), acc3[nt], 0, 0, 0);
        }
    }
    int rowb = wrow + kq * 4;
#pragma unroll
    for (int nt = 0; nt < 4; nt++) {
        int col = nt * 16 + rsel;
        if (col < 60) {
            float bcv = bcls[col];
#pragma unroll
            for (int r = 0; r < 4; r++)
                label[(size_t)(rowb + r) * 60 + col] = acc3[nt][r] + bcv;
        }
    }
}

// ---------------- launch ----------------
extern "C" void kernel_launch(void* const* d_in, const int* in_sizes, int n_in,
                              void* d_out, int out_size, void* d_ws, size_t ws_size,
                              hipStream_t stream) {
    const float* nf   = (const float*)d_in[0];
    const int* src    = (const int*)d_in[1];
    const int* dst    = (const int*)d_in[2];
    const int* n2g    = (const int*)d_in[3];
    const float* Wemb = (const float*)d_in[4];
    const float* bemb = (const float*)d_in[5];
    const float* Wc1  = (const float*)d_in[6];
    const float* bc1  = (const float*)d_in[7];
    const float* Wc2  = (const float*)d_in[8];
    const float* bc2  = (const float*)d_in[9];
    const float* bng  = (const float*)d_in[10];
    const float* bnb  = (const float*)d_in[11];
    const float* bnm  = (const float*)d_in[12];
    const float* bnv  = (const float*)d_in[13];
    const float* Wout = (const float*)d_in[14];
    const float* bout = (const float*)d_in[15];
    const float* Wci  = (const float*)d_in[16];
    const float* bci  = (const float*)d_in[17];
    const float* Wb3a = (const float*)d_in[18];
    const float* bb3a = (const float*)d_in[19];
    const float* Wb3b = (const float*)d_in[20];
    const float* bb3b = (const float*)d_in[21];
    const float* Wcls = (const float*)d_in[22];
    const float* bcls = (const float*)d_in[23];

    char* ws = (char*)d_ws;
    int* deg_out = (int*)(ws + OFF_DEG_OUT);
    int* deg_in  = (int*)(ws + OFF_DEG_IN);
    float* T     = (float*)(ws + OFF_T);
    float* n_out = (float*)(ws + OFF_NOUT);
    float* n_inp = (float*)(ws + OFF_NIN);
    int* row_ptr = (int*)(ws + OFF_ROWPTR);
    int* cursor  = (int*)(ws + OFF_CURSOR);
    int* csr_src = (int*)(ws + OFF_CSRS);
    int* bsum    = (int*)(ws + OFF_BSUM);
    unsigned short* wt2   = (unsigned short*)(ws + OFF_WT2);
    unsigned short* wta   = (unsigned short*)(ws + OFF_WTA);
    unsigned short* wtb   = (unsigned short*)(ws + OFF_WTB);
    unsigned short* wtcls = (unsigned short*)(ws + OFF_WTCLS);
    unsigned short* wot   = (unsigned short*)(ws + OFF_WOT);
    float* bns = (float*)(ws + OFF_BNS);
    float* bnh = (float*)(ws + OFF_BNH);
    float* TAB = (float*)(ws + OFF_TAB);
    float* PP  = (float*)(ws + OFF_PP);
    float* R3  = (float*)(ws + OFF_R3);
    unsigned short* h1w = (unsigned short*)(ws + OFF_H1W);

    float* h3d_out   = (float*)d_out;
    float* label_out = (float*)d_out + (size_t)NN * 3;

    hipMemsetAsync(ws, 0, ZERO_BYTES, stream);   // deg_out, deg_in

    k_deg<<<EBLK, 256, 0, stream>>>(src, dst, deg_out, deg_in);
    k_scan1<<<NBLK, 256, 0, stream>>>(deg_in, row_ptr, bsum);
    k_scan2<<<1, 1024, 0, stream>>>(bsum);
    k_scan3<<<NBLK, 256, 0, stream>>>(row_ptr, bsum, cursor, deg_out, deg_in, n_out, n_inp);
    k_fill<<<EBLK, 256, 0, stream>>>(src, dst, cursor, csr_src);
    k_prep<<<dim3(256, 8), 256, 0, stream>>>(Wc2, Wb3a, Wb3b, wt2, wta, wtb,
                                             Wcls, wtcls, bng, bnb, bnm, bnv, bns, bnh,
                                             Wout, wot, Wemb, bemb, Wc1, bc1, bc2, TAB, PP);
    k_rowstats<<<NBLK, 256, 0, stream>>>(row_ptr, csr_src, n_out, n_inp, nf, T);

    k_conv1<<<NN / 64, 256, 0, stream>>>(T, nf, TAB, n_out, wt2, wot, h1w, R3);
    k_gconv<<<NN / 64, 256, 0, stream>>>(row_ptr, csr_src, n_inp, h1w, PP, bout, R3, h3d_out);
    k_head<<<GG / 64, 256, 0, stream>>>(n2g, h3d_out, Wci, bci, wta, bb3a, wtb, bb3b,
                                        wtcls, bcls, bns, bnh, label_out);
}

// Round 10
// 230.090 us; speedup vs baseline: 1.5114x; 1.0718x over previous
//
#include <hip/hip_runtime.h>

// SimplePoseGNN on MI355X — round 10.
// fp32 in/out; internal bf16 + fp32 accumulation; bf16 MFMA GEMMs.
// conv1: cooperative y-build with WAVE-UNIFORM table reads (scalar s_load broadcast
// via readfirstlane — no ltab LDS, LDS=32KB -> 5 blocks/CU), swizzled tileY,
// GEMM2 (y*n_out)@W2 + Wout residual tile; h1w stored channel-permuted (8B stores).
// k_gconv: register gather + permuted bn/relu + pose dot. k_head: 64-thread blocks
// (512 blocks, full GPU). Graph mean via binary search on sorted node2graph.

#define NN 139264
#define EE 278528
#define GG 8192
#define NBLK 544    // NN/256
#define EBLK 1088   // EE/256

typedef float f32x4 __attribute__((ext_vector_type(4)));
typedef __bf16 bf16x8 __attribute__((ext_vector_type(8)));
typedef unsigned short u16x8 __attribute__((ext_vector_type(8)));
typedef unsigned short u16x4 __attribute__((ext_vector_type(4)));

__device__ __forceinline__ float bf2f(unsigned short u) {
    unsigned int i = ((unsigned int)u) << 16;
    float f;
    __builtin_memcpy(&f, &i, 4);
    return f;
}
__device__ __forceinline__ unsigned short f2bf(float f) {
    unsigned int i;
    __builtin_memcpy(&i, &f, 4);
    i += 0x7fffu + ((i >> 16) & 1u);   // round-to-nearest-even
    return (unsigned short)(i >> 16);
}
__device__ __forceinline__ unsigned short bfbits(float f) {
    __bf16 b = (__bf16)f;
    return __builtin_bit_cast(unsigned short, b);
}

// ---------------- workspace layout (bytes) ----------------
#define OFF_DEG_OUT ((size_t)0)
#define OFF_DEG_IN  ((size_t)557056)
#define ZERO_BYTES  ((size_t)1114112)
#define OFF_T       ((size_t)1114112)
#define OFF_NOUT    ((size_t)2785280)
#define OFF_NIN     ((size_t)3342336)
#define OFF_ROWPTR  ((size_t)3899392)
#define OFF_CURSOR  ((size_t)4460544)
#define OFF_CSRS    ((size_t)5017600)
#define OFF_WT2     ((size_t)6131712)
#define OFF_WTA     ((size_t)6262784)
#define OFF_WTB     ((size_t)6393856)
#define OFF_WTCLS   ((size_t)6524928)
#define OFF_WOT     ((size_t)6557696)
#define OFF_BNS     ((size_t)6565888)
#define OFF_BNH     ((size_t)6572032)
#define OFF_TAB     ((size_t)6578176)
#define OFF_PP      ((size_t)6587392)
#define OFF_BSUM    ((size_t)6595584)
#define OFF_R3      ((size_t)6599680)
#define OFF_H1W     ((size_t)8270848)
// total ~79.6 MB

// ---------------- graph preprocessing ----------------

__global__ void k_deg(const int* __restrict__ src, const int* __restrict__ dst,
                      int* __restrict__ deg_out, int* __restrict__ deg_in) {
    int e = blockIdx.x * 256 + threadIdx.x;
    if (e < EE) {
        atomicAdd(&deg_out[src[e]], 1);
        atomicAdd(&deg_in[dst[e]], 1);
    }
}

__global__ void k_scan1(const int* __restrict__ deg, int* __restrict__ part, int* __restrict__ bsum) {
    __shared__ int sh[256];
    int t = threadIdx.x, gid = blockIdx.x * 256 + t;
    int v = deg[gid];
    sh[t] = v;
    __syncthreads();
#pragma unroll
    for (int off = 1; off < 256; off <<= 1) {
        int a = (t >= off) ? sh[t - off] : 0;
        __syncthreads();
        sh[t] += a;
        __syncthreads();
    }
    part[gid] = sh[t] - v;
    if (t == 255) bsum[blockIdx.x] = sh[t];
}

__global__ void k_scan2(int* __restrict__ bsum) {
    __shared__ int sh[1024];
    int t = threadIdx.x;
    int v = (t < NBLK) ? bsum[t] : 0;
    sh[t] = v;
    __syncthreads();
#pragma unroll
    for (int off = 1; off < 1024; off <<= 1) {
        int a = (t >= off) ? sh[t - off] : 0;
        __syncthreads();
        sh[t] += a;
        __syncthreads();
    }
    if (t < NBLK) bsum[t] = sh[t] - v;
}

__global__ void k_scan3(int* __restrict__ rp, const int* __restrict__ bsum, int* __restrict__ cursor,
                        const int* __restrict__ dego, const int* __restrict__ degi,
                        float* __restrict__ n_out, float* __restrict__ n_in) {
    int t = threadIdx.x, gid = blockIdx.x * 256 + t;
    int v = rp[gid] + bsum[blockIdx.x];
    rp[gid] = v;
    cursor[gid] = v;
    if (gid == 0) rp[NN] = EE;
    n_out[gid] = rsqrtf((float)max(dego[gid], 1));
    n_in[gid]  = rsqrtf((float)max(degi[gid], 1));
}

__global__ void k_fill(const int* __restrict__ src, const int* __restrict__ dst,
                       int* __restrict__ cursor, int* __restrict__ csr) {
    int e = blockIdx.x * 256 + threadIdx.x;
    int d = dst[e];
    int pos = atomicAdd(&cursor[d], 1);
    csr[pos] = src[e];
}

// per-row conv1 stats: T[r] = n_in[r] * { Σ sc*nf0, Σ sc*nf1, Σ sc },  sc = n_out[src]
__global__ void k_rowstats(const int* __restrict__ rp, const int* __restrict__ csr,
                           const float* __restrict__ n_out, const float* __restrict__ n_in,
                           const float* __restrict__ nf, float* __restrict__ T) {
    int r = blockIdx.x * 256 + threadIdx.x;
    int e0 = rp[r], e1 = rp[r + 1];
    float S0 = 0.f, S1 = 0.f, S2 = 0.f;
    for (int e = e0; e < e1; e++) {
        int s = csr[e];
        float sc = n_out[s];
        S0 = fmaf(sc, nf[2 * s], S0);
        S1 = fmaf(sc, nf[2 * s + 1], S1);
        S2 += sc;
    }
    float ni = n_in[r];
    T[3 * r]     = S0 * ni;
    T[3 * r + 1] = S1 * ni;
    T[3 * r + 2] = S2 * ni;
}

// ---------------- weight / bn / table prep ----------------
// TAB layout (floats): [0]ew0s [256]ew1s [512]ew2s [768]c0 [1024]s1 [1280]h1
//                      [1536]we0 [1792]we1 [2048]be     (2304 total)
// PP layout (floats):  [0]bc2p [256]s2p [512]h2p [768]s3p [1024]h3p
//                      [1280]w0p [1536]w1p [1792]w2p    (2048 total)
__global__ void k_prep(const float* __restrict__ Wc2, const float* __restrict__ Wb3a,
                       const float* __restrict__ Wb3b,
                       unsigned short* __restrict__ wt2, unsigned short* __restrict__ wta,
                       unsigned short* __restrict__ wtb,
                       const float* __restrict__ wcls, unsigned short* __restrict__ tcls,
                       const float* __restrict__ g, const float* __restrict__ b,
                       const float* __restrict__ m, const float* __restrict__ v,
                       float* __restrict__ bns, float* __restrict__ bnh,
                       const float* __restrict__ Wout, unsigned short* __restrict__ wot,
                       const float* __restrict__ Wemb, const float* __restrict__ bemb,
                       const float* __restrict__ Wc1, const float* __restrict__ bc1,
                       const float* __restrict__ bc2,
                       float* __restrict__ TAB, float* __restrict__ PP) {
    int t = blockIdx.x * 256 + threadIdx.x;
    int y = blockIdx.y;
    if (y < 3) {
        int k = t >> 8, n = t & 255;
        const float* w = (y == 0) ? Wc2 : (y == 1) ? Wb3a : Wb3b;
        unsigned short* o = (y == 0) ? wt2 : (y == 1) ? wta : wtb;
        o[n * 256 + k] = f2bf(w[t]);
    } else if (y == 3) {
        if (t < 16384) {
            int n = t >> 8, k = t & 255;
            tcls[t] = (n < 60) ? f2bf(wcls[k * 60 + n]) : (unsigned short)0;
        }
    } else if (y == 4) {
        if (t < 1536) {
            float inv = rsqrtf(v[t] + 1e-5f);
            float s = g[t] * inv;
            bns[t] = s;
            bnh[t] = b[t] - m[t] * s;
        }
    } else if (y == 5) {
        if (t < 4096) {
            int n = t >> 8, k = t & 255;
            wot[t] = (n < 3) ? f2bf(Wout[k * 3 + n]) : (unsigned short)0;
        }
    } else if (y == 6) {
        if (t < 256) {
            int c = t;
            float inv0 = rsqrtf(v[c] + 1e-5f);
            float s0 = g[c] * inv0;
            float h0 = b[c] - m[c] * s0;
            float e0 = 0.f, e1 = 0.f, e2 = 0.f;
            for (int k = 0; k < 256; k++) {
                float w = Wc1[k * 256 + c];
                e0 = fmaf(Wemb[k], w, e0);
                e1 = fmaf(Wemb[256 + k], w, e1);
                e2 = fmaf(bemb[k], w, e2);
            }
            TAB[c]        = e0 * s0;
            TAB[256 + c]  = e1 * s0;
            TAB[512 + c]  = e2 * s0;
            TAB[768 + c]  = fmaf(bc1[c], s0, h0);
            float inv1 = rsqrtf(v[256 + c] + 1e-5f);
            float s1 = g[256 + c] * inv1;
            TAB[1024 + c] = s1;
            TAB[1280 + c] = b[256 + c] - m[256 + c] * s1;
            TAB[1536 + c] = Wemb[c];
            TAB[1792 + c] = Wemb[256 + c];
            TAB[2048 + c] = bemb[c];
        }
    } else {
        if (t < 256) {
            int cp = t;                         // permuted index
            int w = cp >> 6, rs = (cp >> 2) & 15, nt = cp & 3;
            int c = w * 64 + nt * 16 + rs;      // actual channel
            PP[cp] = bc2[c];
            float inv2 = rsqrtf(v[512 + c] + 1e-5f);
            float s2 = g[512 + c] * inv2;
            PP[256 + cp] = s2;
            PP[512 + cp] = b[512 + c] - m[512 + c] * s2;
            float inv3 = rsqrtf(v[768 + c] + 1e-5f);
            float s3 = g[768 + c] * inv3;
            PP[768 + cp] = s3;
            PP[1024 + cp] = b[768 + c] - m[768 + c] * s3;
            PP[1280 + cp] = Wout[c * 3];
            PP[1536 + cp] = Wout[c * 3 + 1];
            PP[1792 + cp] = Wout[c * 3 + 2];
        }
    }
}

// ---------------- conv1: cooperative y-build (scalar tables) + GEMM2 + Wout tile ----
__launch_bounds__(256)
__global__ void k_conv1(const float* __restrict__ T, const float* __restrict__ nf,
                        const float* __restrict__ TAB, const float* __restrict__ n_out,
                        const unsigned short* __restrict__ Wt2, const unsigned short* __restrict__ wot,
                        unsigned short* __restrict__ h1w, float* __restrict__ R3) {
    __shared__ unsigned char tileY[64 * 512];
    int lane = threadIdx.x & 63, wave = threadIdx.x >> 6;
    int wrow = blockIdx.x * 64;
    int rsel = lane & 15, kq = lane >> 4;

    // ---- phase 1: thread (wave,lane) builds channels wave*64..+63 of row lane
    {
        int wu = __builtin_amdgcn_readfirstlane(wave);   // wave-uniform -> SGPR
        const float* tb = TAB + wu * 64;                 // this wave's channel base
        int row = wrow + lane;
        float t0 = T[3 * row], t1 = T[3 * row + 1], t2 = T[3 * row + 2];
        float2 p = *(const float2*)(nf + 2 * (size_t)row);
        float f0 = p.x, f1 = p.y;
        float no = n_out[row];
        int sw = (lane & 7) << 4;
        unsigned char* wb = tileY + lane * 512;
#pragma unroll
        for (int jj = 0; jj < 8; jj++) {
            int co = jj * 8;                             // uniform channel offset
            f32x4 ew0a = *(const f32x4*)(tb + co),        ew0b = *(const f32x4*)(tb + co + 4);
            f32x4 ew1a = *(const f32x4*)(tb + 256 + co),  ew1b = *(const f32x4*)(tb + 256 + co + 4);
            f32x4 ew2a = *(const f32x4*)(tb + 512 + co),  ew2b = *(const f32x4*)(tb + 512 + co + 4);
            f32x4 c0a  = *(const f32x4*)(tb + 768 + co),  c0b  = *(const f32x4*)(tb + 768 + co + 4);
            f32x4 s1a  = *(const f32x4*)(tb + 1024 + co), s1b  = *(const f32x4*)(tb + 1024 + co + 4);
            f32x4 h1a  = *(const f32x4*)(tb + 1280 + co), h1b  = *(const f32x4*)(tb + 1280 + co + 4);
            f32x4 w0a  = *(const f32x4*)(tb + 1536 + co), w0b  = *(const f32x4*)(tb + 1536 + co + 4);
            f32x4 w1a  = *(const f32x4*)(tb + 1792 + co), w1b  = *(const f32x4*)(tb + 1792 + co + 4);
            f32x4 bea  = *(const f32x4*)(tb + 2048 + co), beb  = *(const f32x4*)(tb + 2048 + co + 4);
            u16x8 o;
#pragma unroll
            for (int j = 0; j < 4; j++) {
                float z = fmaf(t0, ew0a[j], fmaf(t1, ew1a[j], fmaf(t2, ew2a[j], c0a[j])));
                z = fmaxf(z, 0.f);
                z = fmaxf(fmaf(z, s1a[j], h1a[j]), 0.f);
                float yv = z + fmaf(f0, w0a[j], fmaf(f1, w1a[j], bea[j]));
                o[j] = bfbits(yv * no);
            }
#pragma unroll
            for (int j = 0; j < 4; j++) {
                float z = fmaf(t0, ew0b[j], fmaf(t1, ew1b[j], fmaf(t2, ew2b[j], c0b[j])));
                z = fmaxf(z, 0.f);
                z = fmaxf(fmaf(z, s1b[j], h1b[j]), 0.f);
                float yv = z + fmaf(f0, w0b[j], fmaf(f1, w1b[j], beb[j]));
                o[4 + j] = bfbits(yv * no);
            }
            int cbyte = (wu * 64 + co) * 2;              // uniform part of byte offset
            *(u16x8*)(wb + (cbyte ^ sw)) = o;
        }
    }
    __syncthreads();

    // ---- phase 2: GEMM2 (tileY @ W2) + Wout residual tile (wave 0)
    bool w0w = (wave == 0);
    f32x4 acc[4][4];
    f32x4 acc3[4];
    f32x4 zero = {0.f, 0.f, 0.f, 0.f};
#pragma unroll
    for (int i = 0; i < 4; i++) {
        acc3[i] = zero;
#pragma unroll
        for (int j = 0; j < 4; j++) acc[i][j] = zero;
    }
#pragma unroll
    for (int kt = 0; kt < 8; kt++) {
        int cb = kt * 64 + kq * 16;
        int k0 = kt * 32 + kq * 8;
        bf16x8 afr[4];
#pragma unroll
        for (int mt = 0; mt < 4; mt++) {
            int ar = mt * 16 + rsel;
            u16x8 au = *(const u16x8*)(tileY + ar * 512 + (cb ^ ((ar & 7) << 4)));
            afr[mt] = __builtin_bit_cast(bf16x8, au);
        }
        bf16x8 bfr[4];
#pragma unroll
        for (int nt = 0; nt < 4; nt++) {
            u16x8 bu = *(const u16x8*)(Wt2 + (size_t)(wave * 64 + nt * 16 + rsel) * 256 + k0);
            bfr[nt] = __builtin_bit_cast(bf16x8, bu);
        }
        bf16x8 bw;
        if (w0w) {
            u16x8 bu = *(const u16x8*)(wot + (size_t)rsel * 256 + k0);
            bw = __builtin_bit_cast(bf16x8, bu);
        }
#pragma unroll
        for (int mt = 0; mt < 4; mt++) {
#pragma unroll
            for (int nt = 0; nt < 4; nt++)
                acc[mt][nt] = __builtin_amdgcn_mfma_f32_16x16x32_bf16(afr[mt], bfr[nt], acc[mt][nt], 0, 0, 0);
            if (w0w)
                acc3[mt] = __builtin_amdgcn_mfma_f32_16x16x32_bf16(afr[mt], bw, acc3[mt], 0, 0, 0);
        }
    }

    // permuted coalesced stores: channel c' = wave*64 + rsel*4 + nt
#pragma unroll
    for (int mt = 0; mt < 4; mt++) {
#pragma unroll
        for (int r = 0; r < 4; r++) {
            int row = wrow + mt * 16 + kq * 4 + r;
            u16x4 o;
#pragma unroll
            for (int nt = 0; nt < 4; nt++) o[nt] = bfbits(acc[mt][nt][r]);
            *(u16x4*)(h1w + (size_t)row * 256 + wave * 64 + rsel * 4) = o;
        }
    }

    // R3 from wave 0, lanes rsel<3
    if (w0w && rsel < 3) {
#pragma unroll
        for (int mt = 0; mt < 4; mt++)
#pragma unroll
            for (int r = 0; r < 4; r++) {
                int row = wrow + mt * 16 + kq * 4 + r;
                R3[(size_t)row * 3 + rsel] = acc3[mt][r] / n_out[row];
            }
    }
}

// ---------------- k_gconv: register gather + permuted bn/relu + pose dot ----------
__launch_bounds__(256)
__global__ void k_gconv(const int* __restrict__ rp, const int* __restrict__ csr,
                        const float* __restrict__ n_in, const unsigned short* __restrict__ h1w,
                        const float* __restrict__ PP, const float* __restrict__ bout,
                        const float* __restrict__ R3, float* __restrict__ h3d) {
    int hw = threadIdx.x >> 5;        // 0..7 half-waves
    int l = threadIdx.x & 31;
    int c0 = l * 8;                   // 8 permuted channels per lane

    float bc[8], s0[8], h0[8], s1[8], h1v[8], w0[8], w1[8], w2[8];
#pragma unroll
    for (int j = 0; j < 8; j += 4) {
        *(float4*)(bc + j)  = *(const float4*)(PP + c0 + j);
        *(float4*)(s0 + j)  = *(const float4*)(PP + 256 + c0 + j);
        *(float4*)(h0 + j)  = *(const float4*)(PP + 512 + c0 + j);
        *(float4*)(s1 + j)  = *(const float4*)(PP + 768 + c0 + j);
        *(float4*)(h1v + j) = *(const float4*)(PP + 1024 + c0 + j);
        *(float4*)(w0 + j)  = *(const float4*)(PP + 1280 + c0 + j);
        *(float4*)(w1 + j)  = *(const float4*)(PP + 1536 + c0 + j);
        *(float4*)(w2 + j)  = *(const float4*)(PP + 1792 + c0 + j);
    }
    float b0 = bout[0], b1 = bout[1], b2v = bout[2];

    int rbase = blockIdx.x * 64 + hw * 8;
#pragma unroll 1
    for (int i = 0; i < 8; i++) {
        int row = rbase + i;
        int e0 = rp[row], e1 = rp[row + 1];
        float a[8] = {0.f, 0.f, 0.f, 0.f, 0.f, 0.f, 0.f, 0.f};
        for (int e = e0; e < e1; e++) {
            int s = csr[e];
            u16x8 v = *(const u16x8*)(h1w + ((size_t)s << 8) + c0);
#pragma unroll
            for (int j = 0; j < 8; j++) a[j] += bf2f(v[j]);
        }
        float ni = n_in[row];
        float p0 = 0.f, p1 = 0.f, p2 = 0.f;
#pragma unroll
        for (int j = 0; j < 8; j++) {
            float y = fmaf(a[j], ni, bc[j]);
            y = fmaxf(fmaf(y, s0[j], h0[j]), 0.f);
            y = fmaxf(fmaf(y, s1[j], h1v[j]), 0.f);
            p0 = fmaf(y, w0[j], p0);
            p1 = fmaf(y, w1[j], p1);
            p2 = fmaf(y, w2[j], p2);
        }
#pragma unroll
        for (int m = 1; m < 32; m <<= 1) {
            p0 += __shfl_xor(p0, m, 32);
            p1 += __shfl_xor(p1, m, 32);
            p2 += __shfl_xor(p2, m, 32);
        }
        if (l == 0) {
            size_t o = (size_t)row * 3;
            h3d[o]     = p0 + R3[o]     + b0;
            h3d[o + 1] = p1 + R3[o + 1] + b1;
            h3d[o + 2] = p2 + R3[o + 2] + b2v;
        }
    }
}

// ---------------- fused classification head: 1 wave per block, 16 graphs ----------
__launch_bounds__(64)
__global__ void k_head(const int* __restrict__ n2g, const float* __restrict__ h3d,
                       const float* __restrict__ Wci, const float* __restrict__ bci,
                       const unsigned short* __restrict__ wta, const float* __restrict__ ba,
                       const unsigned short* __restrict__ wtb, const float* __restrict__ bb,
                       const unsigned short* __restrict__ wtcls, const float* __restrict__ bcls,
                       const float* __restrict__ bns, const float* __restrict__ bnh,
                       float* __restrict__ label) {
    __shared__ unsigned char tileA[8192];
    __shared__ unsigned char tileB[8192];
    int lane = threadIdx.x;
    int wrow = blockIdx.x * 16;
    int rsel = lane & 15, kq = lane >> 4;
    int g = wrow + rsel;

    int lo = 0, hi = NN;
    while (lo < hi) { int mid = (lo + hi) >> 1; if (n2g[mid] < g) lo = mid + 1; else hi = mid; }
    int s = lo;
    hi = NN;
    while (lo < hi) { int mid = (lo + hi) >> 1; if (n2g[mid] < g + 1) lo = mid + 1; else hi = mid; }
    int e = lo;
    float m0 = 0.f, m1 = 0.f, m2 = 0.f;
    for (int j = s; j < e; j++) {
        m0 += h3d[(size_t)j * 3];
        m1 += h3d[(size_t)j * 3 + 1];
        m2 += h3d[(size_t)j * 3 + 2];
    }
    float inv = 1.f / fmaxf((float)(e - s), 1.f);
    m0 *= inv; m1 *= inv; m2 *= inv;

    f32x4 zero = {0.f, 0.f, 0.f, 0.f};
    f32x4 acc[16];
#pragma unroll
    for (int i = 0; i < 16; i++) acc[i] = zero;

    // stage 1: z1 = relu(bn4(z0 @ Wa + ba)), z0 built on the fly
#pragma unroll
    for (int kt = 0; kt < 8; kt++) {
        int k0 = kt * 32 + kq * 8;
        u16x8 au;
#pragma unroll
        for (int j = 0; j < 8; j++)
            au[j] = f2bf(fmaf(m0, Wci[k0 + j], fmaf(m1, Wci[256 + k0 + j],
                         fmaf(m2, Wci[512 + k0 + j], bci[k0 + j]))));
        bf16x8 af = __builtin_bit_cast(bf16x8, au);
#pragma unroll
        for (int nt = 0; nt < 16; nt++) {
            u16x8 bu = *(const u16x8*)(wta + (size_t)(nt * 16 + rsel) * 256 + k0);
            acc[nt] = __builtin_amdgcn_mfma_f32_16x16x32_bf16(af, __builtin_bit_cast(bf16x8, bu), acc[nt], 0, 0, 0);
        }
    }
#pragma unroll
    for (int nt = 0; nt < 16; nt++) {
        int col = nt * 16 + rsel;
        float bcv = ba[col];
        float sc = bns[4 * 256 + col], h = bnh[4 * 256 + col];
#pragma unroll
        for (int r = 0; r < 4; r++) {
            float y = fmaxf(fmaf(acc[nt][r] + bcv, sc, h), 0.f);
            int rr = kq * 4 + r;
            *(unsigned short*)(tileA + rr * 512 + ((col * 2) ^ ((rr & 7) << 4))) = f2bf(y);
        }
    }

    // stage 2: z2 = relu(bn5(z1 @ Wb + bb))
#pragma unroll
    for (int i = 0; i < 16; i++) acc[i] = zero;
#pragma unroll
    for (int kt = 0; kt < 8; kt++) {
        int cb = kt * 64 + kq * 16;
        u16x8 au = *(const u16x8*)(tileA + rsel * 512 + (cb ^ ((rsel & 7) << 4)));
        bf16x8 af = __builtin_bit_cast(bf16x8, au);
        int k0 = kt * 32 + kq * 8;
#pragma unroll
        for (int nt = 0; nt < 16; nt++) {
            u16x8 bu = *(const u16x8*)(wtb + (size_t)(nt * 16 + rsel) * 256 + k0);
            acc[nt] = __builtin_amdgcn_mfma_f32_16x16x32_bf16(af, __builtin_bit_cast(bf16x8, bu), acc[nt], 0, 0, 0);
        }
    }
#pragma unroll
    for (int nt = 0; nt < 16; nt++) {
        int col = nt * 16 + rsel;
        float bcv = bb[col];
        float sc = bns[5 * 256 + col], h = bnh[5 * 256 + col];
#pragma unroll
        for (int r = 0; r < 4; r++) {
            float y = fmaxf(fmaf(acc[nt][r] + bcv, sc, h), 0.f);
            int rr = kq * 4 + r;
            *(unsigned short*)(tileB + rr * 512 + ((col * 2) ^ ((rr & 7) << 4))) = f2bf(y);
        }
    }

    // stage 3: label = z2 @ Wcls + bcls (60 cols)
    f32x4 acc3[4];
#pragma unroll
    for (int i = 0; i < 4; i++) acc3[i] = zero;
#pragma unroll
    for (int kt = 0; kt < 8; kt++) {
        int cb = kt * 64 + kq * 16;
        u16x8 au = *(const u16x8*)(tileB + rsel * 512 + (cb ^ ((rsel & 7) << 4)));
        bf16x8 af = __builtin_bit_cast(bf16x8, au);
        int k0 = kt * 32 + kq * 8;
#pragma unroll
        for (int nt = 0; nt < 4; nt++) {
            u16x8 bu = *(const u16x8*)(wtcls + (size_t)(nt * 16 + rsel) * 256 + k0);
            acc3[nt] = __builtin_amdgcn_mfma_f32_16x16x32_bf16(af, __builtin_bit_cast(bf16x8, bu), acc3[nt], 0, 0, 0);
        }
    }
    int rowb = wrow + kq * 4;
#pragma unroll
    for (int nt = 0; nt < 4; nt++) {
        int col = nt * 16 + rsel;
        if (col < 60) {
            float bcv = bcls[col];
#pragma unroll
            for (int r = 0; r < 4; r++)
                label[(size_t)(rowb + r) * 60 + col] = acc3[nt][r] + bcv;
        }
    }
}

// ---------------- launch ----------------
extern "C" void kernel_launch(void* const* d_in, const int* in_sizes, int n_in,
                              void* d_out, int out_size, void* d_ws, size_t ws_size,
                              hipStream_t stream) {
    const float* nf   = (const float*)d_in[0];
    const int* src    = (const int*)d_in[1];
    const int* dst    = (const int*)d_in[2];
    const int* n2g    = (const int*)d_in[3];
    const float* Wemb = (const float*)d_in[4];
    const float* bemb = (const float*)d_in[5];
    const float* Wc1  = (const float*)d_in[6];
    const float* bc1  = (const float*)d_in[7];
    const float* Wc2  = (const float*)d_in[8];
    const float* bc2  = (const float*)d_in[9];
    const float* bng  = (const float*)d_in[10];
    const float* bnb  = (const float*)d_in[11];
    const float* bnm  = (const float*)d_in[12];
    const float* bnv  = (const float*)d_in[13];
    const float* Wout = (const float*)d_in[14];
    const float* bout = (const float*)d_in[15];
    const float* Wci  = (const float*)d_in[16];
    const float* bci  = (const float*)d_in[17];
    const float* Wb3a = (const float*)d_in[18];
    const float* bb3a = (const float*)d_in[19];
    const float* Wb3b = (const float*)d_in[20];
    const float* bb3b = (const float*)d_in[21];
    const float* Wcls = (const float*)d_in[22];
    const float* bcls = (const float*)d_in[23];

    char* ws = (char*)d_ws;
    int* deg_out = (int*)(ws + OFF_DEG_OUT);
    int* deg_in  = (int*)(ws + OFF_DEG_IN);
    float* T     = (float*)(ws + OFF_T);
    float* n_out = (float*)(ws + OFF_NOUT);
    float* n_inp = (float*)(ws + OFF_NIN);
    int* row_ptr = (int*)(ws + OFF_ROWPTR);
    int* cursor  = (int*)(ws + OFF_CURSOR);
    int* csr_src = (int*)(ws + OFF_CSRS);
    int* bsum    = (int*)(ws + OFF_BSUM);
    unsigned short* wt2   = (unsigned short*)(ws + OFF_WT2);
    unsigned short* wta   = (unsigned short*)(ws + OFF_WTA);
    unsigned short* wtb   = (unsigned short*)(ws + OFF_WTB);
    unsigned short* wtcls = (unsigned short*)(ws + OFF_WTCLS);
    unsigned short* wot   = (unsigned short*)(ws + OFF_WOT);
    float* bns = (float*)(ws + OFF_BNS);
    float* bnh = (float*)(ws + OFF_BNH);
    float* TAB = (float*)(ws + OFF_TAB);
    float* PP  = (float*)(ws + OFF_PP);
    float* R3  = (float*)(ws + OFF_R3);
    unsigned short* h1w = (unsigned short*)(ws + OFF_H1W);

    float* h3d_out   = (float*)d_out;
    float* label_out = (float*)d_out + (size_t)NN * 3;

    hipMemsetAsync(ws, 0, ZERO_BYTES, stream);   // deg_out, deg_in

    k_deg<<<EBLK, 256, 0, stream>>>(src, dst, deg_out, deg_in);
    k_scan1<<<NBLK, 256, 0, stream>>>(deg_in, row_ptr, bsum);
    k_scan2<<<1, 1024, 0, stream>>>(bsum);
    k_scan3<<<NBLK, 256, 0, stream>>>(row_ptr, bsum, cursor, deg_out, deg_in, n_out, n_inp);
    k_fill<<<EBLK, 256, 0, stream>>>(src, dst, cursor, csr_src);
    k_prep<<<dim3(256, 8), 256, 0, stream>>>(Wc2, Wb3a, Wb3b, wt2, wta, wtb,
                                             Wcls, wtcls, bng, bnb, bnm, bnv, bns, bnh,
                                             Wout, wot, Wemb, bemb, Wc1, bc1, bc2, TAB, PP);
    k_rowstats<<<NBLK, 256, 0, stream>>>(row_ptr, csr_src, n_out, n_inp, nf, T);

    k_conv1<<<NN / 64, 256, 0, stream>>>(T, nf, TAB, n_out, wt2, wot, h1w, R3);
    k_gconv<<<NN / 64, 256, 0, stream>>>(row_ptr, csr_src, n_inp, h1w, PP, bout, R3, h3d_out);
    k_head<<<GG / 16, 64, 0, stream>>>(n2g, h3d_out, Wci, bci, wta, bb3a, wtb, bb3b,
                                       wtcls, bcls, bns, bnh, label_out);
}